// Round 4
// baseline (1301.435 us; speedup 1.0000x reference)
//
#include <hip/hip_runtime.h>
#include <math.h>

// ---------------- workspace layout (bytes) ----------------
constexpr size_t XW_OFF  = 0;                                   // 65536*384 f32 = 96 MB (dead after 2nd gru -> reused for norms)
constexpr size_t O1_OFF  = XW_OFF + 65536ull * 384 * 4;         // 32 MB
constexpr size_t O2_OFF  = O1_OFF + 512ull * 128 * 128 * 4;     // 32 MB
constexpr size_t Y0_OFF  = O2_OFF + 512ull * 128 * 128 * 4;     // 128 KB
constexpr size_t Y1_OFF  = Y0_OFF + 256ull * 128 * 4;           // 128 KB
constexpr size_t MMD_OFF = Y1_OFF + 256ull * 128 * 4;           // 1 KB
constexpr size_t WTS_OFF = MMD_OFF + 256 * 4;                   // 1 KB
constexpr size_t BW_OFF  = WTS_OFF + 256 * 4;                   // 1 KB
constexpr size_t NRM_OFF = XW_OFF;                              // norms[2][128][512] f32 = 512 KB (aliases xw)

// ---------------- K1/K3: C[M][N] = A[M][K] @ W[N][K]^T + bias[N] ----------------
__global__ __launch_bounds__(256) void gemm64(const float* __restrict__ A,
                                              const float* __restrict__ W,
                                              const float* __restrict__ bias,
                                              float* __restrict__ C,
                                              int M, int N, int K)
{
    __shared__ __align__(16) float As[64][36];
    __shared__ __align__(16) float Ws[64][36];
    const int tid = threadIdx.x;
    const int tx = tid & 15, ty = tid >> 4;
    const int m0 = blockIdx.x * 64, n0 = blockIdx.y * 64;

    float acc[4][4];
#pragma unroll
    for (int i = 0; i < 4; ++i)
#pragma unroll
        for (int j = 0; j < 4; ++j) acc[i][j] = 0.f;

#pragma unroll 1
    for (int kc = 0; kc < K; kc += 32) {
#pragma unroll
        for (int it = 0; it < 2; ++it) {
            int idx = tid + it * 256;          // 0..511
            int row = idx >> 3;
            int c4  = (idx & 7) * 4;
            float4 va = *(const float4*)(A + (size_t)(m0 + row) * K + kc + c4);
            *(float4*)&As[row][c4] = va;
            float4 vw = *(const float4*)(W + (size_t)(n0 + row) * K + kc + c4);
            *(float4*)&Ws[row][c4] = vw;
        }
        __syncthreads();
#pragma unroll 1
        for (int k0 = 0; k0 < 32; k0 += 4) {
            float4 a4[4], w4[4];
#pragma unroll
            for (int i = 0; i < 4; ++i) a4[i] = *(float4*)&As[ty + 16 * i][k0];
#pragma unroll
            for (int j = 0; j < 4; ++j) w4[j] = *(float4*)&Ws[tx + 16 * j][k0];
#pragma unroll
            for (int i = 0; i < 4; ++i)
#pragma unroll
                for (int j = 0; j < 4; ++j) {
                    acc[i][j] += a4[i].x * w4[j].x + a4[i].y * w4[j].y +
                                 a4[i].z * w4[j].z + a4[i].w * w4[j].w;
                }
        }
        __syncthreads();
    }
#pragma unroll
    for (int i = 0; i < 4; ++i)
#pragma unroll
        for (int j = 0; j < 4; ++j) {
            int r = m0 + ty + 16 * i, c = n0 + tx + 16 * j;
            C[(size_t)r * N + c] = acc[i][j] + bias[c];
        }
}

// ---------------- K2/K4: GRU scan, one block per batch row ----------------
// Weight row held in 32 NAMED float4 registers (VGPR-stationary; the r3 profile
// showed VGPR=80 < 128 -> compiler was re-fetching whh from L2 every step).
__global__ __launch_bounds__(384, 2) void gru_scan(const float* __restrict__ xw,
                                                   const float* __restrict__ whh,
                                                   const float* __restrict__ bhh,
                                                   float* __restrict__ out)
{
    const int b = blockIdx.x;
    const int j = threadIdx.x;
    const float* wr = whh + (size_t)j * 128;

#define LDW(i) float4 w##i = *(const float4*)(wr + 4 * i);
    LDW(0)  LDW(1)  LDW(2)  LDW(3)  LDW(4)  LDW(5)  LDW(6)  LDW(7)
    LDW(8)  LDW(9)  LDW(10) LDW(11) LDW(12) LDW(13) LDW(14) LDW(15)
    LDW(16) LDW(17) LDW(18) LDW(19) LDW(20) LDW(21) LDW(22) LDW(23)
    LDW(24) LDW(25) LDW(26) LDW(27) LDW(28) LDW(29) LDW(30) LDW(31)
#undef LDW

    const float bj = bhh[j];
    __shared__ __align__(16) float h_s[128];
    __shared__ float rz_s[256];
    __shared__ float xn_s[128];
    __shared__ float hn_s[128];
    if (j < 128) h_s[j] = 0.f;
    __syncthreads();

    const float* xwb = xw + (size_t)b * 128 * 384;
    const int g = j >> 7, u = j & 127;

    float xv = xwb[j];   // prefetch t=0

#pragma unroll 1
    for (int t = 0; t < 128; ++t) {
        // prefetch next step's x (covers HBM latency under this step's FMAs)
        float xv_next = 0.f;
        if (t < 127) xv_next = xwb[(t + 1) * 384 + j];

        float a0 = 0.f, a1 = 0.f, a2 = 0.f, a3 = 0.f;
#define FMA4(i, p) { float4 hv = *(float4*)&h_s[4 * i];                         \
                     a##p += w##i.x * hv.x + w##i.y * hv.y +                    \
                             w##i.z * hv.z + w##i.w * hv.w; }
        FMA4(0, 0)  FMA4(1, 1)  FMA4(2, 2)  FMA4(3, 3)
        FMA4(4, 0)  FMA4(5, 1)  FMA4(6, 2)  FMA4(7, 3)
        FMA4(8, 0)  FMA4(9, 1)  FMA4(10, 2) FMA4(11, 3)
        FMA4(12, 0) FMA4(13, 1) FMA4(14, 2) FMA4(15, 3)
        FMA4(16, 0) FMA4(17, 1) FMA4(18, 2) FMA4(19, 3)
        FMA4(20, 0) FMA4(21, 1) FMA4(22, 2) FMA4(23, 3)
        FMA4(24, 0) FMA4(25, 1) FMA4(26, 2) FMA4(27, 3)
        FMA4(28, 0) FMA4(29, 1) FMA4(30, 2) FMA4(31, 3)
#undef FMA4
        float acc = bj + ((a0 + a1) + (a2 + a3));

        if (g == 0)      rz_s[u] = xv + acc;
        else if (g == 1) rz_s[128 + u] = xv + acc;
        else             { xn_s[u] = xv; hn_s[u] = acc; }
        __syncthreads();
        if (j < 128) {
            float r = 1.f / (1.f + __expf(-rz_s[j]));
            float z = 1.f / (1.f + __expf(-rz_s[128 + j]));
            float xa = xn_s[j] + r * hn_s[j];
            float e = __expf(-2.f * fabsf(xa));
            float th = (1.f - e) / (1.f + e);
            th = copysignf(th, xa);
            float hnew = (1.f - z) * th + z * h_s[j];
            h_s[j] = hnew;
            out[((size_t)b * 128 + t) * 128 + j] = hnew;
        }
        __syncthreads();
        xv = xv_next;
    }
}

// ---------------- K5: y[256][128] += xall @ gw^T (split-K, atomic) ----------------
__global__ __launch_bounds__(256) void gate_gemm(const float* __restrict__ o,
                                                 const float* __restrict__ gw,
                                                 float* __restrict__ y)
{
    __shared__ __align__(16) float As[64][36];
    __shared__ __align__(16) float Ws[64][36];
    const int tid = threadIdx.x;
    const int tx = tid & 15, ty = tid >> 4;
    const int m0 = blockIdx.x * 64, n0 = blockIdx.y * 64;
    const int k0beg = blockIdx.z * 1024;

    float acc[4][4];
#pragma unroll
    for (int i = 0; i < 4; ++i)
#pragma unroll
        for (int j = 0; j < 4; ++j) acc[i][j] = 0.f;

#pragma unroll 1
    for (int kc = k0beg; kc < k0beg + 1024; kc += 32) {
#pragma unroll
        for (int it = 0; it < 2; ++it) {
            int idx = tid + it * 256;
            int row = idx >> 3;
            int c4  = (idx & 7) * 4;
            int kap = kc + c4;
            int s = kap >> 8, half = (kap >> 7) & 1, h = kap & 127;
            float4 va = *(const float4*)(o + ((size_t)(m0 + row + 256 * half) * 128 + s) * 128 + h);
            *(float4*)&As[row][c4] = va;
            float4 vw = *(const float4*)(gw + (size_t)(n0 + row) * 32768 + kap);
            *(float4*)&Ws[row][c4] = vw;
        }
        __syncthreads();
#pragma unroll 1
        for (int k0 = 0; k0 < 32; k0 += 4) {
            float4 a4[4], w4[4];
#pragma unroll
            for (int i = 0; i < 4; ++i) a4[i] = *(float4*)&As[ty + 16 * i][k0];
#pragma unroll
            for (int j = 0; j < 4; ++j) w4[j] = *(float4*)&Ws[tx + 16 * j][k0];
#pragma unroll
            for (int i = 0; i < 4; ++i)
#pragma unroll
                for (int j = 0; j < 4; ++j) {
                    acc[i][j] += a4[i].x * w4[j].x + a4[i].y * w4[j].y +
                                 a4[i].z * w4[j].z + a4[i].w * w4[j].w;
                }
        }
        __syncthreads();
    }
#pragma unroll
    for (int i = 0; i < 4; ++i)
#pragma unroll
        for (int j = 0; j < 4; ++j) {
            int r = m0 + ty + 16 * i, c = n0 + tx + 16 * j;
            atomicAdd(&y[r * 128 + c], acc[i][j]);
        }
}

// ---------------- K6: BN + sigmoid-mean + softmax -> weights (128) ----------------
__global__ void gate_reduce(const float* __restrict__ y,
                            const float* __restrict__ gamma,
                            const float* __restrict__ beta,
                            float* __restrict__ wts_ws,
                            float* __restrict__ wts_out)
{
    const int o = threadIdx.x;   // 128 threads
    float sum = 0.f, sumsq = 0.f;
    for (int b = 0; b < 256; ++b) {
        float v = y[b * 128 + o];
        sum += v; sumsq += v * v;
    }
    float m = sum * (1.f / 256.f);
    float var = sumsq * (1.f / 256.f) - m * m;
    float inv = rsqrtf(var + 1e-5f);
    float g = gamma[o], be = beta[o];
    float sw = 0.f;
    for (int b = 0; b < 256; ++b) {
        float v = y[b * 128 + o];
        float t = g * (v - m) * inv + be;
        sw += 1.f / (1.f + __expf(-t));
    }
    float wo = sw * (1.f / 256.f);

    __shared__ float red[128];
    red[o] = wo;
    __syncthreads();
    for (int st = 64; st > 0; st >>= 1) {
        if (o < st) red[o] = fmaxf(red[o], red[o + st]);
        __syncthreads();
    }
    float mx = red[0];
    __syncthreads();
    float e = __expf(wo - mx);
    red[o] = e;
    __syncthreads();
    for (int st = 64; st > 0; st >>= 1) {
        if (o < st) red[o] += red[o + st];
        __syncthreads();
    }
    float r = e / red[0];
    wts_ws[o] = r;
    wts_out[o] = r;
}

// ---------------- K7: fc_out = o2[:, -1, :] @ fc_w^T + fc_b ----------------
__global__ void fc_kern(const float* __restrict__ o2,
                        const float* __restrict__ fw,
                        const float* __restrict__ fb,
                        float* __restrict__ out)
{
    int gid = blockIdx.x * blockDim.x + threadIdx.x;
    if (gid >= 3072) return;
    int b = gid / 6, oo = gid - b * 6;
    const float* xr = o2 + ((size_t)b * 128 + 127) * 128;
    const float* wr = fw + oo * 128;
    float acc = fb[oo];
#pragma unroll 16
    for (int k = 0; k < 128; ++k) acc += xr[k] * wr[k];
    out[gid] = acc;
}

// ---------------- K8a: per-row norms ----------------
__global__ __launch_bounds__(512) void row_norms(const float* __restrict__ o1,
                                                 const float* __restrict__ o2,
                                                 float* __restrict__ norms)
{
    const int s = blockIdx.x;          // 128
    const int l = blockIdx.y;          // 2
    const float* o = l ? o2 : o1;
    const int i = threadIdx.x;         // 512 rows
    const float* r = o + ((size_t)i * 128 + s) * 128;
    float acc = 0.f;
#pragma unroll
    for (int k = 0; k < 128; k += 4) {
        float4 v = *(const float4*)(r + k);
        acc += v.x * v.x + v.y * v.y + v.z * v.z + v.w * v.w;
    }
    norms[((size_t)l * 128 + s) * 512 + i] = acc;
}

// ---------------- K8b: per-pair bandwidth ----------------
__global__ void pair_stats(const float* __restrict__ o1,
                           const float* __restrict__ o2,
                           float* __restrict__ bw)
{
    const int p = blockIdx.x;          // 256 pairs
    const int l = p >> 7, s = p & 127;
    const float* o = l ? o2 : o1;
    const int tid = threadIdx.x;       // 256
    const int h = tid & 127, half = tid >> 7;

    float acc_u = 0.f, acc_sq = 0.f;
    for (int r = 0; r < 256; ++r) {
        int i = half * 256 + r;
        float v = o[((size_t)i * 128 + s) * 128 + h];
        acc_u += v; acc_sq += v * v;
    }
    __shared__ float u2[256];
    __shared__ float red[256];
    u2[tid] = acc_u;
    red[tid] = acc_sq;
    __syncthreads();
    for (int st = 128; st > 0; st >>= 1) {
        if (tid < st) red[tid] += red[tid + st];
        __syncthreads();
    }
    float S1 = red[0];
    __syncthreads();
    float uu = 0.f;
    if (tid < 128) { float t = u2[tid] + u2[tid + 128]; uu = t * t; }
    red[tid] = uu;
    __syncthreads();
    for (int st = 128; st > 0; st >>= 1) {
        if (tid < st) red[tid] += red[tid + st];
        __syncthreads();
    }
    if (tid == 0) {
        float S2 = red[0];
        float d2s = 1024.f * S1 - 2.f * S2;
        bw[p] = d2s / (512.f * 512.f - 512.f) * 0.25f;
    }
}

// ---------------- K9: MMD Gram + 5-kernel sum, symmetric tiles ----------------
__global__ __launch_bounds__(256) void mmd_kern(const float* __restrict__ o1,
                                                const float* __restrict__ o2,
                                                const float* __restrict__ norms,
                                                const float* __restrict__ bw,
                                                float* __restrict__ mmdv)
{
    const int lin = blockIdx.x;               // 0..2559
    const int v   = (lin & 7) * 320 + (lin >> 3);
    const int p   = v / 10;                   // pair
    const int tp  = v - p * 10;               // tile-pair
    int ti, tj;
    if (tp < 4)      { ti = 0; tj = tp; }
    else if (tp < 7) { ti = 1; tj = tp - 3; }
    else if (tp < 9) { ti = 2; tj = tp - 5; }
    else             { ti = 3; tj = 3; }
    const int l = p >> 7, s = p & 127;
    const float* o = l ? o2 : o1;
    const float sgn  = ((ti < 2) == (tj < 2)) ? 1.f : -1.f;
    const float coef = sgn * ((ti == tj) ? 1.f : 2.f);

    __shared__ __align__(16) float As[128][36];
    __shared__ __align__(16) float Bs[128][36];
    __shared__ float rbuf[4];

    const int tid = threadIdx.x;
    const int tx = tid & 15, ty = tid >> 4;

    float acc[8][8];
#pragma unroll
    for (int i = 0; i < 8; ++i)
#pragma unroll
        for (int j = 0; j < 8; ++j) acc[i][j] = 0.f;

#pragma unroll 1
    for (int kc = 0; kc < 128; kc += 32) {
#pragma unroll
        for (int it = 0; it < 4; ++it) {
            int idx = tid + it * 256;           // 0..1023
            int row = idx >> 3;
            int c4  = (idx & 7) * 4;
            float4 va = *(const float4*)(o + ((size_t)(ti * 128 + row) * 128 + s) * 128 + kc + c4);
            *(float4*)&As[row][c4] = va;
            float4 vb = *(const float4*)(o + ((size_t)(tj * 128 + row) * 128 + s) * 128 + kc + c4);
            *(float4*)&Bs[row][c4] = vb;
        }
        __syncthreads();
#pragma unroll 1
        for (int k0 = 0; k0 < 32; k0 += 4) {
            float4 b4[8];
#pragma unroll
            for (int j = 0; j < 8; ++j) b4[j] = *(float4*)&Bs[tx + 16 * j][k0];
#pragma unroll
            for (int i = 0; i < 8; ++i) {
                float4 a4 = *(float4*)&As[ty + 16 * i][k0];
#pragma unroll
                for (int j = 0; j < 8; ++j) {
                    acc[i][j] += a4.x * b4[j].x + a4.y * b4[j].y +
                                 a4.z * b4[j].z + a4.w * b4[j].w;
                }
            }
        }
        __syncthreads();
    }

    const float* np_ = norms + (size_t)p * 512;
    float na[8], nb[8];
#pragma unroll
    for (int i = 0; i < 8; ++i) na[i] = np_[ti * 128 + ty + 16 * i];
#pragma unroll
    for (int j = 0; j < 8; ++j) nb[j] = np_[tj * 128 + tx + 16 * j];

    const float bwv = bw[p];
    float c0 = -1.f / bwv;
    float c1 = c0 * 0.5f, c2 = c1 * 0.5f, c3 = c2 * 0.5f, c4v = c3 * 0.5f;
    float tot = 0.f;
#pragma unroll 1
    for (int i = 0; i < 8; ++i) {
#pragma unroll
        for (int j = 0; j < 8; ++j) {
            float d2 = na[i] + nb[j] - 2.f * acc[i][j];
            float kv = __expf(c0 * d2) + __expf(c1 * d2) + __expf(c2 * d2) +
                       __expf(c3 * d2) + __expf(c4v * d2);
            tot += kv;
        }
    }
    tot *= coef;

    for (int off = 32; off > 0; off >>= 1) tot += __shfl_down(tot, off);
    if ((tid & 63) == 0) rbuf[tid >> 6] = tot;
    __syncthreads();
    if (tid == 0) atomicAdd(&mmdv[p], rbuf[0] + rbuf[1] + rbuf[2] + rbuf[3]);
}

// ---------------- K10: loss = sum(wts * mmd) / 65536 ----------------
__global__ void final_loss(const float* __restrict__ wts,
                           const float* __restrict__ mmdv,
                           float* __restrict__ out)
{
    const int t = threadIdx.x;  // 256
    float v = wts[t] * mmdv[t];
    __shared__ float red[256];
    red[t] = v;
    __syncthreads();
    for (int st = 128; st > 0; st >>= 1) {
        if (t < st) red[t] += red[t + st];
        __syncthreads();
    }
    if (t == 0) out[0] = red[0] * (1.f / 65536.f);
}

// ---------------- launch ----------------
extern "C" void kernel_launch(void* const* d_in, const int* in_sizes, int n_in,
                              void* d_out, int out_size, void* d_ws, size_t ws_size,
                              hipStream_t stream)
{
    (void)in_sizes; (void)n_in; (void)out_size; (void)ws_size;
    const float* x    = (const float*)d_in[0];
    const float* wih0 = (const float*)d_in[1];
    const float* whh0 = (const float*)d_in[2];
    const float* bih0 = (const float*)d_in[3];
    const float* bhh0 = (const float*)d_in[4];
    const float* wih1 = (const float*)d_in[5];
    const float* whh1 = (const float*)d_in[6];
    const float* bih1 = (const float*)d_in[7];
    const float* bhh1 = (const float*)d_in[8];
    const float* gw0  = (const float*)d_in[9];
    const float* bg0  = (const float*)d_in[11];
    const float* bb0  = (const float*)d_in[12];
    const float* gw1  = (const float*)d_in[13];
    const float* bg1  = (const float*)d_in[15];
    const float* bb1  = (const float*)d_in[16];
    const float* fcw  = (const float*)d_in[17];
    const float* fcb  = (const float*)d_in[18];

    float* out = (float*)d_out;
    char*  ws  = (char*)d_ws;
    float* xw   = (float*)(ws + XW_OFF);
    float* o1   = (float*)(ws + O1_OFF);
    float* o2   = (float*)(ws + O2_OFF);
    float* y0   = (float*)(ws + Y0_OFF);
    float* y1   = (float*)(ws + Y1_OFF);
    float* mmdv = (float*)(ws + MMD_OFF);
    float* wts  = (float*)(ws + WTS_OFF);
    float* bwv  = (float*)(ws + BW_OFF);
    float* nrm  = (float*)(ws + NRM_OFF);   // aliases xw; valid after 2nd gru_scan

    hipMemsetAsync(y0, 0, (256 * 128 * 2 + 256) * sizeof(float), stream);

    gemm64<<<dim3(1024, 6), 256, 0, stream>>>(x, wih0, bih0, xw, 65536, 384, 128);
    gru_scan<<<512, 384, 0, stream>>>(xw, whh0, bhh0, o1);
    gemm64<<<dim3(1024, 6), 256, 0, stream>>>(o1, wih1, bih1, xw, 65536, 384, 128);
    gru_scan<<<512, 384, 0, stream>>>(xw, whh1, bhh1, o2);

    gate_gemm<<<dim3(4, 2, 32), 256, 0, stream>>>(o1, gw0, y0);
    gate_gemm<<<dim3(4, 2, 32), 256, 0, stream>>>(o2, gw1, y1);
    gate_reduce<<<1, 128, 0, stream>>>(y0, bg0, bb0, wts, out + 3073);
    gate_reduce<<<1, 128, 0, stream>>>(y1, bg1, bb1, wts + 128, out + 3073 + 128);

    fc_kern<<<12, 256, 0, stream>>>(o2, fcw, fcb, out);

    row_norms<<<dim3(128, 2), 512, 0, stream>>>(o1, o2, nrm);   // xw dead from here
    pair_stats<<<256, 256, 0, stream>>>(o1, o2, bwv);
    mmd_kern<<<2560, 256, 0, stream>>>(o1, o2, nrm, bwv, mmdv);
    final_loss<<<1, 256, 0, stream>>>(wts, mmdv, out + 3072);
}

// Round 5
// 1144.110 us; speedup vs baseline: 1.1375x; 1.1375x over previous
//
#include <hip/hip_runtime.h>
#include <math.h>

// ---------------- workspace layout (bytes) ----------------
constexpr size_t XW_OFF  = 0;                                   // 65536*384 f32 = 96 MB (dead after 2nd gru -> reused for norms)
constexpr size_t O1_OFF  = XW_OFF + 65536ull * 384 * 4;         // 32 MB
constexpr size_t O2_OFF  = O1_OFF + 512ull * 128 * 128 * 4;     // 32 MB
constexpr size_t Y0_OFF  = O2_OFF + 512ull * 128 * 128 * 4;     // 128 KB
constexpr size_t Y1_OFF  = Y0_OFF + 256ull * 128 * 4;           // 128 KB
constexpr size_t MMD_OFF = Y1_OFF + 256ull * 128 * 4;           // 1 KB
constexpr size_t WTS_OFF = MMD_OFF + 256 * 4;                   // 1 KB
constexpr size_t BW_OFF  = WTS_OFF + 256 * 4;                   // 1 KB
constexpr size_t NRM_OFF = XW_OFF;                              // norms[2][128][512] f32 = 512 KB (aliases xw)

// ---------------- K1/K3: C[M][N] = A[M][K] @ W[N][K]^T + bias[N] ----------------
__global__ __launch_bounds__(256) void gemm64(const float* __restrict__ A,
                                              const float* __restrict__ W,
                                              const float* __restrict__ bias,
                                              float* __restrict__ C,
                                              int M, int N, int K)
{
    __shared__ __align__(16) float As[64][36];
    __shared__ __align__(16) float Ws[64][36];
    const int tid = threadIdx.x;
    const int tx = tid & 15, ty = tid >> 4;
    const int m0 = blockIdx.x * 64, n0 = blockIdx.y * 64;

    float acc[4][4];
#pragma unroll
    for (int i = 0; i < 4; ++i)
#pragma unroll
        for (int j = 0; j < 4; ++j) acc[i][j] = 0.f;

#pragma unroll 1
    for (int kc = 0; kc < K; kc += 32) {
#pragma unroll
        for (int it = 0; it < 2; ++it) {
            int idx = tid + it * 256;          // 0..511
            int row = idx >> 3;
            int c4  = (idx & 7) * 4;
            float4 va = *(const float4*)(A + (size_t)(m0 + row) * K + kc + c4);
            *(float4*)&As[row][c4] = va;
            float4 vw = *(const float4*)(W + (size_t)(n0 + row) * K + kc + c4);
            *(float4*)&Ws[row][c4] = vw;
        }
        __syncthreads();
#pragma unroll 1
        for (int k0 = 0; k0 < 32; k0 += 4) {
            float4 a4[4], w4[4];
#pragma unroll
            for (int i = 0; i < 4; ++i) a4[i] = *(float4*)&As[ty + 16 * i][k0];
#pragma unroll
            for (int j = 0; j < 4; ++j) w4[j] = *(float4*)&Ws[tx + 16 * j][k0];
#pragma unroll
            for (int i = 0; i < 4; ++i)
#pragma unroll
                for (int j = 0; j < 4; ++j) {
                    acc[i][j] += a4[i].x * w4[j].x + a4[i].y * w4[j].y +
                                 a4[i].z * w4[j].z + a4[i].w * w4[j].w;
                }
        }
        __syncthreads();
    }
#pragma unroll
    for (int i = 0; i < 4; ++i)
#pragma unroll
        for (int j = 0; j < 4; ++j) {
            int r = m0 + ty + 16 * i, c = n0 + tx + 16 * j;
            C[(size_t)r * N + c] = acc[i][j] + bias[c];
        }
}

// ---------------- K2/K4: GRU scan ----------------
// 2 batch rows per block, 384 threads. Thread t: outputs j in {4*og..4*og+3},
// k-slice [32*ks, 32*ks+32) where og=t>>2, ks=t&3. Weight slice = 32 float4,
// pinned in VGPRs via asm (r4 post-mortem: un-pinned loads get re-sunk into
// the loop). Each h b128 read feeds 16 FMAs (was 4) -> LDS traffic /4.
// Partial sums reduced over the 4-lane ks cluster via shfl_xor; lane ks keeps
// output j = 4*og+ks = t, so gate logic keeps the j==t mapping.
__global__ __launch_bounds__(384, 1) void gru_scan(const float* __restrict__ xw,
                                                   const float* __restrict__ whh,
                                                   const float* __restrict__ bhh,
                                                   float* __restrict__ out)
{
    const int b0 = blockIdx.x * 2;
    const int t  = threadIdx.x;            // output j = t
    const int og = t >> 2, ks = t & 3;

    const float* wbase = whh + (size_t)(4 * og) * 128 + 32 * ks;

#define DECLROW(r) \
    float4 w##r##_0 = *(const float4*)(wbase + (r) * 128 +  0); \
    float4 w##r##_1 = *(const float4*)(wbase + (r) * 128 +  4); \
    float4 w##r##_2 = *(const float4*)(wbase + (r) * 128 +  8); \
    float4 w##r##_3 = *(const float4*)(wbase + (r) * 128 + 12); \
    float4 w##r##_4 = *(const float4*)(wbase + (r) * 128 + 16); \
    float4 w##r##_5 = *(const float4*)(wbase + (r) * 128 + 20); \
    float4 w##r##_6 = *(const float4*)(wbase + (r) * 128 + 24); \
    float4 w##r##_7 = *(const float4*)(wbase + (r) * 128 + 28);
    DECLROW(0) DECLROW(1) DECLROW(2) DECLROW(3)
#undef DECLROW

#define PIN(v) asm volatile("" : "+v"(v.x), "+v"(v.y), "+v"(v.z), "+v"(v.w))
#define PINROW(r) PIN(w##r##_0); PIN(w##r##_1); PIN(w##r##_2); PIN(w##r##_3); \
                  PIN(w##r##_4); PIN(w##r##_5); PIN(w##r##_6); PIN(w##r##_7);
    PINROW(0) PINROW(1) PINROW(2) PINROW(3)
#undef PINROW
#undef PIN

    const float bj = bhh[t];

    __shared__ __align__(16) float h_s[2][128];
    __shared__ float rz_s[2][256];
    __shared__ float xn_s[2][128];
    __shared__ float hn_s[2][128];
    if (t < 128) { h_s[0][t] = 0.f; h_s[1][t] = 0.f; }
    __syncthreads();

    const float* xwb0 = xw + (size_t)b0 * 128 * 384;
    const float* xwb1 = xwb0 + 128 * 384;
    const int g = t >> 7, u = t & 127;

    float xv0 = xwb0[t], xv1 = xwb1[t];   // prefetch step 0

#pragma unroll 1
    for (int st = 0; st < 128; ++st) {
        float nx0 = 0.f, nx1 = 0.f;
        if (st < 127) {
            nx0 = xwb0[(st + 1) * 384 + t];
            nx1 = xwb1[(st + 1) * 384 + t];
        }

#define MQ(q, hp) { float4 hv = *(const float4*)((hp) + 4 * (q));                    \
        a0 += w0_##q.x * hv.x + w0_##q.y * hv.y + w0_##q.z * hv.z + w0_##q.w * hv.w; \
        a1 += w1_##q.x * hv.x + w1_##q.y * hv.y + w1_##q.z * hv.z + w1_##q.w * hv.w; \
        a2 += w2_##q.x * hv.x + w2_##q.y * hv.y + w2_##q.z * hv.z + w2_##q.w * hv.w; \
        a3 += w3_##q.x * hv.x + w3_##q.y * hv.y + w3_##q.z * hv.z + w3_##q.w * hv.w; }

        // ---- batch row 0 ----
        const float* hp0 = &h_s[0][32 * ks];
        float a0 = 0.f, a1 = 0.f, a2 = 0.f, a3 = 0.f;
        MQ(0, hp0) MQ(1, hp0) MQ(2, hp0) MQ(3, hp0)
        MQ(4, hp0) MQ(5, hp0) MQ(6, hp0) MQ(7, hp0)
        a0 += __shfl_xor(a0, 1); a0 += __shfl_xor(a0, 2);
        a1 += __shfl_xor(a1, 1); a1 += __shfl_xor(a1, 2);
        a2 += __shfl_xor(a2, 1); a2 += __shfl_xor(a2, 2);
        a3 += __shfl_xor(a3, 1); a3 += __shfl_xor(a3, 2);
        float hw0 = ((ks == 0) ? a0 : (ks == 1) ? a1 : (ks == 2) ? a2 : a3) + bj;

        // ---- batch row 1 ----
        const float* hp1 = &h_s[1][32 * ks];
        a0 = 0.f; a1 = 0.f; a2 = 0.f; a3 = 0.f;
        MQ(0, hp1) MQ(1, hp1) MQ(2, hp1) MQ(3, hp1)
        MQ(4, hp1) MQ(5, hp1) MQ(6, hp1) MQ(7, hp1)
        a0 += __shfl_xor(a0, 1); a0 += __shfl_xor(a0, 2);
        a1 += __shfl_xor(a1, 1); a1 += __shfl_xor(a1, 2);
        a2 += __shfl_xor(a2, 1); a2 += __shfl_xor(a2, 2);
        a3 += __shfl_xor(a3, 1); a3 += __shfl_xor(a3, 2);
        float hw1 = ((ks == 0) ? a0 : (ks == 1) ? a1 : (ks == 2) ? a2 : a3) + bj;
#undef MQ

        if (g == 0)      { rz_s[0][u] = xv0 + hw0;        rz_s[1][u] = xv1 + hw1; }
        else if (g == 1) { rz_s[0][128 + u] = xv0 + hw0;  rz_s[1][128 + u] = xv1 + hw1; }
        else             { xn_s[0][u] = xv0; hn_s[0][u] = hw0;
                           xn_s[1][u] = xv1; hn_s[1][u] = hw1; }
        __syncthreads();
        if (t < 256) {
            const int rr = t >> 7, uu = t & 127;
            float r = 1.f / (1.f + __expf(-rz_s[rr][uu]));
            float z = 1.f / (1.f + __expf(-rz_s[rr][128 + uu]));
            float xa = xn_s[rr][uu] + r * hn_s[rr][uu];
            float e = __expf(-2.f * fabsf(xa));
            float th = (1.f - e) / (1.f + e);
            th = copysignf(th, xa);
            float hnew = (1.f - z) * th + z * h_s[rr][uu];
            h_s[rr][uu] = hnew;
            out[((size_t)(b0 + rr) * 128 + st) * 128 + uu] = hnew;
        }
        __syncthreads();
        xv0 = nx0; xv1 = nx1;
    }
}

// ---------------- K5: y[256][128] += xall @ gw^T (split-K, atomic) ----------------
__global__ __launch_bounds__(256) void gate_gemm(const float* __restrict__ o,
                                                 const float* __restrict__ gw,
                                                 float* __restrict__ y)
{
    __shared__ __align__(16) float As[64][36];
    __shared__ __align__(16) float Ws[64][36];
    const int tid = threadIdx.x;
    const int tx = tid & 15, ty = tid >> 4;
    const int m0 = blockIdx.x * 64, n0 = blockIdx.y * 64;
    const int k0beg = blockIdx.z * 1024;

    float acc[4][4];
#pragma unroll
    for (int i = 0; i < 4; ++i)
#pragma unroll
        for (int j = 0; j < 4; ++j) acc[i][j] = 0.f;

#pragma unroll 1
    for (int kc = k0beg; kc < k0beg + 1024; kc += 32) {
#pragma unroll
        for (int it = 0; it < 2; ++it) {
            int idx = tid + it * 256;
            int row = idx >> 3;
            int c4  = (idx & 7) * 4;
            int kap = kc + c4;
            int s = kap >> 8, half = (kap >> 7) & 1, h = kap & 127;
            float4 va = *(const float4*)(o + ((size_t)(m0 + row + 256 * half) * 128 + s) * 128 + h);
            *(float4*)&As[row][c4] = va;
            float4 vw = *(const float4*)(gw + (size_t)(n0 + row) * 32768 + kap);
            *(float4*)&Ws[row][c4] = vw;
        }
        __syncthreads();
#pragma unroll 1
        for (int k0 = 0; k0 < 32; k0 += 4) {
            float4 a4[4], w4[4];
#pragma unroll
            for (int i = 0; i < 4; ++i) a4[i] = *(float4*)&As[ty + 16 * i][k0];
#pragma unroll
            for (int j = 0; j < 4; ++j) w4[j] = *(float4*)&Ws[tx + 16 * j][k0];
#pragma unroll
            for (int i = 0; i < 4; ++i)
#pragma unroll
                for (int j = 0; j < 4; ++j) {
                    acc[i][j] += a4[i].x * w4[j].x + a4[i].y * w4[j].y +
                                 a4[i].z * w4[j].z + a4[i].w * w4[j].w;
                }
        }
        __syncthreads();
    }
#pragma unroll
    for (int i = 0; i < 4; ++i)
#pragma unroll
        for (int j = 0; j < 4; ++j) {
            int r = m0 + ty + 16 * i, c = n0 + tx + 16 * j;
            atomicAdd(&y[r * 128 + c], acc[i][j]);
        }
}

// ---------------- K6: BN + sigmoid-mean + softmax -> weights (128) ----------------
__global__ void gate_reduce(const float* __restrict__ y,
                            const float* __restrict__ gamma,
                            const float* __restrict__ beta,
                            float* __restrict__ wts_ws,
                            float* __restrict__ wts_out)
{
    const int o = threadIdx.x;   // 128 threads
    float sum = 0.f, sumsq = 0.f;
    for (int b = 0; b < 256; ++b) {
        float v = y[b * 128 + o];
        sum += v; sumsq += v * v;
    }
    float m = sum * (1.f / 256.f);
    float var = sumsq * (1.f / 256.f) - m * m;
    float inv = rsqrtf(var + 1e-5f);
    float g = gamma[o], be = beta[o];
    float sw = 0.f;
    for (int b = 0; b < 256; ++b) {
        float v = y[b * 128 + o];
        float t = g * (v - m) * inv + be;
        sw += 1.f / (1.f + __expf(-t));
    }
    float wo = sw * (1.f / 256.f);

    __shared__ float red[128];
    red[o] = wo;
    __syncthreads();
    for (int st = 64; st > 0; st >>= 1) {
        if (o < st) red[o] = fmaxf(red[o], red[o + st]);
        __syncthreads();
    }
    float mx = red[0];
    __syncthreads();
    float e = __expf(wo - mx);
    red[o] = e;
    __syncthreads();
    for (int st = 64; st > 0; st >>= 1) {
        if (o < st) red[o] += red[o + st];
        __syncthreads();
    }
    float r = e / red[0];
    wts_ws[o] = r;
    wts_out[o] = r;
}

// ---------------- K7: fc_out = o2[:, -1, :] @ fc_w^T + fc_b ----------------
__global__ void fc_kern(const float* __restrict__ o2,
                        const float* __restrict__ fw,
                        const float* __restrict__ fb,
                        float* __restrict__ out)
{
    int gid = blockIdx.x * blockDim.x + threadIdx.x;
    if (gid >= 3072) return;
    int b = gid / 6, oo = gid - b * 6;
    const float* xr = o2 + ((size_t)b * 128 + 127) * 128;
    const float* wr = fw + oo * 128;
    float acc = fb[oo];
#pragma unroll 16
    for (int k = 0; k < 128; ++k) acc += xr[k] * wr[k];
    out[gid] = acc;
}

// ---------------- K8a: per-row norms ----------------
__global__ __launch_bounds__(512) void row_norms(const float* __restrict__ o1,
                                                 const float* __restrict__ o2,
                                                 float* __restrict__ norms)
{
    const int s = blockIdx.x;          // 128
    const int l = blockIdx.y;          // 2
    const float* o = l ? o2 : o1;
    const int i = threadIdx.x;         // 512 rows
    const float* r = o + ((size_t)i * 128 + s) * 128;
    float acc = 0.f;
#pragma unroll
    for (int k = 0; k < 128; k += 4) {
        float4 v = *(const float4*)(r + k);
        acc += v.x * v.x + v.y * v.y + v.z * v.z + v.w * v.w;
    }
    norms[((size_t)l * 128 + s) * 512 + i] = acc;
}

// ---------------- K8b: per-pair bandwidth ----------------
__global__ void pair_stats(const float* __restrict__ o1,
                           const float* __restrict__ o2,
                           float* __restrict__ bw)
{
    const int p = blockIdx.x;          // 256 pairs
    const int l = p >> 7, s = p & 127;
    const float* o = l ? o2 : o1;
    const int tid = threadIdx.x;       // 256
    const int h = tid & 127, half = tid >> 7;

    float acc_u = 0.f, acc_sq = 0.f;
    for (int r = 0; r < 256; ++r) {
        int i = half * 256 + r;
        float v = o[((size_t)i * 128 + s) * 128 + h];
        acc_u += v; acc_sq += v * v;
    }
    __shared__ float u2[256];
    __shared__ float red[256];
    u2[tid] = acc_u;
    red[tid] = acc_sq;
    __syncthreads();
    for (int st = 128; st > 0; st >>= 1) {
        if (tid < st) red[tid] += red[tid + st];
        __syncthreads();
    }
    float S1 = red[0];
    __syncthreads();
    float uu = 0.f;
    if (tid < 128) { float t = u2[tid] + u2[tid + 128]; uu = t * t; }
    red[tid] = uu;
    __syncthreads();
    for (int st = 128; st > 0; st >>= 1) {
        if (tid < st) red[tid] += red[tid + st];
        __syncthreads();
    }
    if (tid == 0) {
        float S2 = red[0];
        float d2s = 1024.f * S1 - 2.f * S2;
        bw[p] = d2s / (512.f * 512.f - 512.f) * 0.25f;
    }
}

// ---------------- K9: MMD Gram + 5-kernel sum, symmetric tiles ----------------
__global__ __launch_bounds__(256) void mmd_kern(const float* __restrict__ o1,
                                                const float* __restrict__ o2,
                                                const float* __restrict__ norms,
                                                const float* __restrict__ bw,
                                                float* __restrict__ mmdv)
{
    const int lin = blockIdx.x;               // 0..2559
    const int v   = (lin & 7) * 320 + (lin >> 3);
    const int p   = v / 10;                   // pair
    const int tp  = v - p * 10;               // tile-pair
    int ti, tj;
    if (tp < 4)      { ti = 0; tj = tp; }
    else if (tp < 7) { ti = 1; tj = tp - 3; }
    else if (tp < 9) { ti = 2; tj = tp - 5; }
    else             { ti = 3; tj = 3; }
    const int l = p >> 7, s = p & 127;
    const float* o = l ? o2 : o1;
    const float sgn  = ((ti < 2) == (tj < 2)) ? 1.f : -1.f;
    const float coef = sgn * ((ti == tj) ? 1.f : 2.f);

    __shared__ __align__(16) float As[128][36];
    __shared__ __align__(16) float Bs[128][36];
    __shared__ float rbuf[4];

    const int tid = threadIdx.x;
    const int tx = tid & 15, ty = tid >> 4;

    float acc[8][8];
#pragma unroll
    for (int i = 0; i < 8; ++i)
#pragma unroll
        for (int j = 0; j < 8; ++j) acc[i][j] = 0.f;

#pragma unroll 1
    for (int kc = 0; kc < 128; kc += 32) {
#pragma unroll
        for (int it = 0; it < 4; ++it) {
            int idx = tid + it * 256;           // 0..1023
            int row = idx >> 3;
            int c4  = (idx & 7) * 4;
            float4 va = *(const float4*)(o + ((size_t)(ti * 128 + row) * 128 + s) * 128 + kc + c4);
            *(float4*)&As[row][c4] = va;
            float4 vb = *(const float4*)(o + ((size_t)(tj * 128 + row) * 128 + s) * 128 + kc + c4);
            *(float4*)&Bs[row][c4] = vb;
        }
        __syncthreads();
#pragma unroll 1
        for (int k0 = 0; k0 < 32; k0 += 4) {
            float4 b4[8];
#pragma unroll
            for (int j = 0; j < 8; ++j) b4[j] = *(float4*)&Bs[tx + 16 * j][k0];
#pragma unroll
            for (int i = 0; i < 8; ++i) {
                float4 a4 = *(float4*)&As[ty + 16 * i][k0];
#pragma unroll
                for (int j = 0; j < 8; ++j) {
                    acc[i][j] += a4.x * b4[j].x + a4.y * b4[j].y +
                                 a4.z * b4[j].z + a4.w * b4[j].w;
                }
            }
        }
        __syncthreads();
    }

    const float* np_ = norms + (size_t)p * 512;
    float na[8], nb[8];
#pragma unroll
    for (int i = 0; i < 8; ++i) na[i] = np_[ti * 128 + ty + 16 * i];
#pragma unroll
    for (int j = 0; j < 8; ++j) nb[j] = np_[tj * 128 + tx + 16 * j];

    const float bwv = bw[p];
    float c0 = -1.f / bwv;
    float c1 = c0 * 0.5f, c2 = c1 * 0.5f, c3 = c2 * 0.5f, c4v = c3 * 0.5f;
    float tot = 0.f;
#pragma unroll 1
    for (int i = 0; i < 8; ++i) {
#pragma unroll
        for (int j = 0; j < 8; ++j) {
            float d2 = na[i] + nb[j] - 2.f * acc[i][j];
            float kv = __expf(c0 * d2) + __expf(c1 * d2) + __expf(c2 * d2) +
                       __expf(c3 * d2) + __expf(c4v * d2);
            tot += kv;
        }
    }
    tot *= coef;

    for (int off = 32; off > 0; off >>= 1) tot += __shfl_down(tot, off);
    if ((tid & 63) == 0) rbuf[tid >> 6] = tot;
    __syncthreads();
    if (tid == 0) atomicAdd(&mmdv[p], rbuf[0] + rbuf[1] + rbuf[2] + rbuf[3]);
}

// ---------------- K10: loss = sum(wts * mmd) / 65536 ----------------
__global__ void final_loss(const float* __restrict__ wts,
                           const float* __restrict__ mmdv,
                           float* __restrict__ out)
{
    const int t = threadIdx.x;  // 256
    float v = wts[t] * mmdv[t];
    __shared__ float red[256];
    red[t] = v;
    __syncthreads();
    for (int st = 128; st > 0; st >>= 1) {
        if (t < st) red[t] += red[t + st];
        __syncthreads();
    }
    if (t == 0) out[0] = red[0] * (1.f / 65536.f);
}

// ---------------- launch ----------------
extern "C" void kernel_launch(void* const* d_in, const int* in_sizes, int n_in,
                              void* d_out, int out_size, void* d_ws, size_t ws_size,
                              hipStream_t stream)
{
    (void)in_sizes; (void)n_in; (void)out_size; (void)ws_size;
    const float* x    = (const float*)d_in[0];
    const float* wih0 = (const float*)d_in[1];
    const float* whh0 = (const float*)d_in[2];
    const float* bih0 = (const float*)d_in[3];
    const float* bhh0 = (const float*)d_in[4];
    const float* wih1 = (const float*)d_in[5];
    const float* whh1 = (const float*)d_in[6];
    const float* bih1 = (const float*)d_in[7];
    const float* bhh1 = (const float*)d_in[8];
    const float* gw0  = (const float*)d_in[9];
    const float* bg0  = (const float*)d_in[11];
    const float* bb0  = (const float*)d_in[12];
    const float* gw1  = (const float*)d_in[13];
    const float* bg1  = (const float*)d_in[15];
    const float* bb1  = (const float*)d_in[16];
    const float* fcw  = (const float*)d_in[17];
    const float* fcb  = (const float*)d_in[18];

    float* out = (float*)d_out;
    char*  ws  = (char*)d_ws;
    float* xw   = (float*)(ws + XW_OFF);
    float* o1   = (float*)(ws + O1_OFF);
    float* o2   = (float*)(ws + O2_OFF);
    float* y0   = (float*)(ws + Y0_OFF);
    float* y1   = (float*)(ws + Y1_OFF);
    float* mmdv = (float*)(ws + MMD_OFF);
    float* wts  = (float*)(ws + WTS_OFF);
    float* bwv  = (float*)(ws + BW_OFF);
    float* nrm  = (float*)(ws + NRM_OFF);   // aliases xw; valid after 2nd gru_scan

    hipMemsetAsync(y0, 0, (256 * 128 * 2 + 256) * sizeof(float), stream);

    gemm64<<<dim3(1024, 6), 256, 0, stream>>>(x, wih0, bih0, xw, 65536, 384, 128);
    gru_scan<<<256, 384, 0, stream>>>(xw, whh0, bhh0, o1);
    gemm64<<<dim3(1024, 6), 256, 0, stream>>>(o1, wih1, bih1, xw, 65536, 384, 128);
    gru_scan<<<256, 384, 0, stream>>>(xw, whh1, bhh1, o2);

    gate_gemm<<<dim3(4, 2, 32), 256, 0, stream>>>(o1, gw0, y0);
    gate_gemm<<<dim3(4, 2, 32), 256, 0, stream>>>(o2, gw1, y1);
    gate_reduce<<<1, 128, 0, stream>>>(y0, bg0, bb0, wts, out + 3073);
    gate_reduce<<<1, 128, 0, stream>>>(y1, bg1, bb1, wts + 128, out + 3073 + 128);

    fc_kern<<<12, 256, 0, stream>>>(o2, fcw, fcb, out);

    row_norms<<<dim3(128, 2), 512, 0, stream>>>(o1, o2, nrm);   // xw dead from here
    pair_stats<<<256, 256, 0, stream>>>(o1, o2, bwv);
    mmd_kern<<<2560, 256, 0, stream>>>(o1, o2, nrm, bwv, mmdv);
    final_loss<<<1, 256, 0, stream>>>(wts, mmdv, out + 3072);
}

// Round 6
// 1077.504 us; speedup vs baseline: 1.2078x; 1.0618x over previous
//
#include <hip/hip_runtime.h>
#include <math.h>

// ---------------- workspace layout (bytes) ----------------
constexpr size_t XW_OFF  = 0;                                   // 65536*384 f32 = 96 MB (dead after 2nd gru -> reused for norms)
constexpr size_t O1_OFF  = XW_OFF + 65536ull * 384 * 4;         // 32 MB
constexpr size_t O2_OFF  = O1_OFF + 512ull * 128 * 128 * 4;     // 32 MB
constexpr size_t Y0_OFF  = O2_OFF + 512ull * 128 * 128 * 4;     // 128 KB
constexpr size_t Y1_OFF  = Y0_OFF + 256ull * 128 * 4;           // 128 KB
constexpr size_t MMD_OFF = Y1_OFF + 256ull * 128 * 4;           // 1 KB
constexpr size_t WTS_OFF = MMD_OFF + 256 * 4;                   // 1 KB
constexpr size_t BW_OFF  = WTS_OFF + 256 * 4;                   // 1 KB
constexpr size_t NRM_OFF = XW_OFF;                              // norms[2][128][512] f32 = 512 KB (aliases xw)

// ---------------- K1/K3: C[M][N] = A[M][K] @ W[N][K]^T + bias[N] ----------------
__global__ __launch_bounds__(256) void gemm64(const float* __restrict__ A,
                                              const float* __restrict__ W,
                                              const float* __restrict__ bias,
                                              float* __restrict__ C,
                                              int M, int N, int K)
{
    __shared__ __align__(16) float As[64][36];
    __shared__ __align__(16) float Ws[64][36];
    const int tid = threadIdx.x;
    const int tx = tid & 15, ty = tid >> 4;
    const int m0 = blockIdx.x * 64, n0 = blockIdx.y * 64;

    float acc[4][4];
#pragma unroll
    for (int i = 0; i < 4; ++i)
#pragma unroll
        for (int j = 0; j < 4; ++j) acc[i][j] = 0.f;

#pragma unroll 1
    for (int kc = 0; kc < K; kc += 32) {
#pragma unroll
        for (int it = 0; it < 2; ++it) {
            int idx = tid + it * 256;          // 0..511
            int row = idx >> 3;
            int c4  = (idx & 7) * 4;
            float4 va = *(const float4*)(A + (size_t)(m0 + row) * K + kc + c4);
            *(float4*)&As[row][c4] = va;
            float4 vw = *(const float4*)(W + (size_t)(n0 + row) * K + kc + c4);
            *(float4*)&Ws[row][c4] = vw;
        }
        __syncthreads();
#pragma unroll 1
        for (int k0 = 0; k0 < 32; k0 += 4) {
            float4 a4[4], w4[4];
#pragma unroll
            for (int i = 0; i < 4; ++i) a4[i] = *(float4*)&As[ty + 16 * i][k0];
#pragma unroll
            for (int j = 0; j < 4; ++j) w4[j] = *(float4*)&Ws[tx + 16 * j][k0];
#pragma unroll
            for (int i = 0; i < 4; ++i)
#pragma unroll
                for (int j = 0; j < 4; ++j) {
                    acc[i][j] += a4[i].x * w4[j].x + a4[i].y * w4[j].y +
                                 a4[i].z * w4[j].z + a4[i].w * w4[j].w;
                }
        }
        __syncthreads();
    }
#pragma unroll
    for (int i = 0; i < 4; ++i)
#pragma unroll
        for (int j = 0; j < 4; ++j) {
            int r = m0 + ty + 16 * i, c = n0 + tx + 16 * j;
            C[(size_t)r * N + c] = acc[i][j] + bias[c];
        }
}

// ---------------- K2/K4: GRU scan ----------------
// 2 batch rows per block, 384 threads. Thread t: outputs j in {4*og..4*og+3},
// k-slice [32*ks, 32*ks+32) where og=t>>2, ks=t&3. Weight slice = 32 float4,
// pinned in VGPRs via asm. Each h b128 read feeds 16 FMAs.
__global__ __launch_bounds__(384, 1) void gru_scan(const float* __restrict__ xw,
                                                   const float* __restrict__ whh,
                                                   const float* __restrict__ bhh,
                                                   float* __restrict__ out)
{
    const int b0 = blockIdx.x * 2;
    const int t  = threadIdx.x;            // output j = t
    const int og = t >> 2, ks = t & 3;

    const float* wbase = whh + (size_t)(4 * og) * 128 + 32 * ks;

#define DECLROW(r) \
    float4 w##r##_0 = *(const float4*)(wbase + (r) * 128 +  0); \
    float4 w##r##_1 = *(const float4*)(wbase + (r) * 128 +  4); \
    float4 w##r##_2 = *(const float4*)(wbase + (r) * 128 +  8); \
    float4 w##r##_3 = *(const float4*)(wbase + (r) * 128 + 12); \
    float4 w##r##_4 = *(const float4*)(wbase + (r) * 128 + 16); \
    float4 w##r##_5 = *(const float4*)(wbase + (r) * 128 + 20); \
    float4 w##r##_6 = *(const float4*)(wbase + (r) * 128 + 24); \
    float4 w##r##_7 = *(const float4*)(wbase + (r) * 128 + 28);
    DECLROW(0) DECLROW(1) DECLROW(2) DECLROW(3)
#undef DECLROW

#define PIN(v) asm volatile("" : "+v"(v.x), "+v"(v.y), "+v"(v.z), "+v"(v.w))
#define PINROW(r) PIN(w##r##_0); PIN(w##r##_1); PIN(w##r##_2); PIN(w##r##_3); \
                  PIN(w##r##_4); PIN(w##r##_5); PIN(w##r##_6); PIN(w##r##_7);
    PINROW(0) PINROW(1) PINROW(2) PINROW(3)
#undef PINROW
#undef PIN

    const float bj = bhh[t];

    __shared__ __align__(16) float h_s[2][128];
    __shared__ float rz_s[2][256];
    __shared__ float xn_s[2][128];
    __shared__ float hn_s[2][128];
    if (t < 128) { h_s[0][t] = 0.f; h_s[1][t] = 0.f; }
    __syncthreads();

    const float* xwb0 = xw + (size_t)b0 * 128 * 384;
    const float* xwb1 = xwb0 + 128 * 384;
    const int g = t >> 7, u = t & 127;

    float xv0 = xwb0[t], xv1 = xwb1[t];   // prefetch step 0

#pragma unroll 1
    for (int st = 0; st < 128; ++st) {
        float nx0 = 0.f, nx1 = 0.f;
        if (st < 127) {
            nx0 = xwb0[(st + 1) * 384 + t];
            nx1 = xwb1[(st + 1) * 384 + t];
        }

#define MQ(q, hp) { float4 hv = *(const float4*)((hp) + 4 * (q));                    \
        a0 += w0_##q.x * hv.x + w0_##q.y * hv.y + w0_##q.z * hv.z + w0_##q.w * hv.w; \
        a1 += w1_##q.x * hv.x + w1_##q.y * hv.y + w1_##q.z * hv.z + w1_##q.w * hv.w; \
        a2 += w2_##q.x * hv.x + w2_##q.y * hv.y + w2_##q.z * hv.z + w2_##q.w * hv.w; \
        a3 += w3_##q.x * hv.x + w3_##q.y * hv.y + w3_##q.z * hv.z + w3_##q.w * hv.w; }

        // ---- batch row 0 ----
        const float* hp0 = &h_s[0][32 * ks];
        float a0 = 0.f, a1 = 0.f, a2 = 0.f, a3 = 0.f;
        MQ(0, hp0) MQ(1, hp0) MQ(2, hp0) MQ(3, hp0)
        MQ(4, hp0) MQ(5, hp0) MQ(6, hp0) MQ(7, hp0)
        a0 += __shfl_xor(a0, 1); a0 += __shfl_xor(a0, 2);
        a1 += __shfl_xor(a1, 1); a1 += __shfl_xor(a1, 2);
        a2 += __shfl_xor(a2, 1); a2 += __shfl_xor(a2, 2);
        a3 += __shfl_xor(a3, 1); a3 += __shfl_xor(a3, 2);
        float hw0 = ((ks == 0) ? a0 : (ks == 1) ? a1 : (ks == 2) ? a2 : a3) + bj;

        // ---- batch row 1 ----
        const float* hp1 = &h_s[1][32 * ks];
        a0 = 0.f; a1 = 0.f; a2 = 0.f; a3 = 0.f;
        MQ(0, hp1) MQ(1, hp1) MQ(2, hp1) MQ(3, hp1)
        MQ(4, hp1) MQ(5, hp1) MQ(6, hp1) MQ(7, hp1)
        a0 += __shfl_xor(a0, 1); a0 += __shfl_xor(a0, 2);
        a1 += __shfl_xor(a1, 1); a1 += __shfl_xor(a1, 2);
        a2 += __shfl_xor(a2, 1); a2 += __shfl_xor(a2, 2);
        a3 += __shfl_xor(a3, 1); a3 += __shfl_xor(a3, 2);
        float hw1 = ((ks == 0) ? a0 : (ks == 1) ? a1 : (ks == 2) ? a2 : a3) + bj;
#undef MQ

        if (g == 0)      { rz_s[0][u] = xv0 + hw0;        rz_s[1][u] = xv1 + hw1; }
        else if (g == 1) { rz_s[0][128 + u] = xv0 + hw0;  rz_s[1][128 + u] = xv1 + hw1; }
        else             { xn_s[0][u] = xv0; hn_s[0][u] = hw0;
                           xn_s[1][u] = xv1; hn_s[1][u] = hw1; }
        __syncthreads();
        if (t < 256) {
            const int rr = t >> 7, uu = t & 127;
            float r = 1.f / (1.f + __expf(-rz_s[rr][uu]));
            float z = 1.f / (1.f + __expf(-rz_s[rr][128 + uu]));
            float xa = xn_s[rr][uu] + r * hn_s[rr][uu];
            float e = __expf(-2.f * fabsf(xa));
            float th = (1.f - e) / (1.f + e);
            th = copysignf(th, xa);
            float hnew = (1.f - z) * th + z * h_s[rr][uu];
            h_s[rr][uu] = hnew;
            out[((size_t)(b0 + rr) * 128 + st) * 128 + uu] = hnew;
        }
        __syncthreads();
        xv0 = nx0; xv1 = nx1;
    }
}

// ---------------- K5: y[256][128] += xall @ gw^T (split-K, atomic) ----------------
__global__ __launch_bounds__(256) void gate_gemm(const float* __restrict__ o,
                                                 const float* __restrict__ gw,
                                                 float* __restrict__ y)
{
    __shared__ __align__(16) float As[64][36];
    __shared__ __align__(16) float Ws[64][36];
    const int tid = threadIdx.x;
    const int tx = tid & 15, ty = tid >> 4;
    const int m0 = blockIdx.x * 64, n0 = blockIdx.y * 64;
    const int k0beg = blockIdx.z * 1024;

    float acc[4][4];
#pragma unroll
    for (int i = 0; i < 4; ++i)
#pragma unroll
        for (int j = 0; j < 4; ++j) acc[i][j] = 0.f;

#pragma unroll 1
    for (int kc = k0beg; kc < k0beg + 1024; kc += 32) {
#pragma unroll
        for (int it = 0; it < 2; ++it) {
            int idx = tid + it * 256;
            int row = idx >> 3;
            int c4  = (idx & 7) * 4;
            int kap = kc + c4;
            int s = kap >> 8, half = (kap >> 7) & 1, h = kap & 127;
            float4 va = *(const float4*)(o + ((size_t)(m0 + row + 256 * half) * 128 + s) * 128 + h);
            *(float4*)&As[row][c4] = va;
            float4 vw = *(const float4*)(gw + (size_t)(n0 + row) * 32768 + kap);
            *(float4*)&Ws[row][c4] = vw;
        }
        __syncthreads();
#pragma unroll 1
        for (int k0 = 0; k0 < 32; k0 += 4) {
            float4 a4[4], w4[4];
#pragma unroll
            for (int i = 0; i < 4; ++i) a4[i] = *(float4*)&As[ty + 16 * i][k0];
#pragma unroll
            for (int j = 0; j < 4; ++j) w4[j] = *(float4*)&Ws[tx + 16 * j][k0];
#pragma unroll
            for (int i = 0; i < 4; ++i)
#pragma unroll
                for (int j = 0; j < 4; ++j) {
                    acc[i][j] += a4[i].x * w4[j].x + a4[i].y * w4[j].y +
                                 a4[i].z * w4[j].z + a4[i].w * w4[j].w;
                }
        }
        __syncthreads();
    }
#pragma unroll
    for (int i = 0; i < 4; ++i)
#pragma unroll
        for (int j = 0; j < 4; ++j) {
            int r = m0 + ty + 16 * i, c = n0 + tx + 16 * j;
            atomicAdd(&y[r * 128 + c], acc[i][j]);
        }
}

// ---------------- K6: BN + sigmoid-mean + softmax -> weights (128) ----------------
__global__ void gate_reduce(const float* __restrict__ y,
                            const float* __restrict__ gamma,
                            const float* __restrict__ beta,
                            float* __restrict__ wts_ws,
                            float* __restrict__ wts_out)
{
    const int o = threadIdx.x;   // 128 threads
    float sum = 0.f, sumsq = 0.f;
    for (int b = 0; b < 256; ++b) {
        float v = y[b * 128 + o];
        sum += v; sumsq += v * v;
    }
    float m = sum * (1.f / 256.f);
    float var = sumsq * (1.f / 256.f) - m * m;
    float inv = rsqrtf(var + 1e-5f);
    float g = gamma[o], be = beta[o];
    float sw = 0.f;
    for (int b = 0; b < 256; ++b) {
        float v = y[b * 128 + o];
        float t = g * (v - m) * inv + be;
        sw += 1.f / (1.f + __expf(-t));
    }
    float wo = sw * (1.f / 256.f);

    __shared__ float red[128];
    red[o] = wo;
    __syncthreads();
    for (int st = 64; st > 0; st >>= 1) {
        if (o < st) red[o] = fmaxf(red[o], red[o + st]);
        __syncthreads();
    }
    float mx = red[0];
    __syncthreads();
    float e = __expf(wo - mx);
    red[o] = e;
    __syncthreads();
    for (int st = 64; st > 0; st >>= 1) {
        if (o < st) red[o] += red[o + st];
        __syncthreads();
    }
    float r = e / red[0];
    wts_ws[o] = r;
    wts_out[o] = r;
}

// ---------------- K7: fc_out = o2[:, -1, :] @ fc_w^T + fc_b ----------------
__global__ void fc_kern(const float* __restrict__ o2,
                        const float* __restrict__ fw,
                        const float* __restrict__ fb,
                        float* __restrict__ out)
{
    int gid = blockIdx.x * blockDim.x + threadIdx.x;
    if (gid >= 3072) return;
    int b = gid / 6, oo = gid - b * 6;
    const float* xr = o2 + ((size_t)b * 128 + 127) * 128;
    const float* wr = fw + oo * 128;
    float acc = fb[oo];
#pragma unroll 16
    for (int k = 0; k < 128; ++k) acc += xr[k] * wr[k];
    out[gid] = acc;
}

// ---------------- K8a: per-row norms ----------------
__global__ __launch_bounds__(512) void row_norms(const float* __restrict__ o1,
                                                 const float* __restrict__ o2,
                                                 float* __restrict__ norms)
{
    const int s = blockIdx.x;          // 128
    const int l = blockIdx.y;          // 2
    const float* o = l ? o2 : o1;
    const int i = threadIdx.x;         // 512 rows
    const float* r = o + ((size_t)i * 128 + s) * 128;
    float acc = 0.f;
#pragma unroll
    for (int k = 0; k < 128; k += 4) {
        float4 v = *(const float4*)(r + k);
        acc += v.x * v.x + v.y * v.y + v.z * v.z + v.w * v.w;
    }
    norms[((size_t)l * 128 + s) * 512 + i] = acc;
}

// ---------------- K8b: per-pair bandwidth ----------------
__global__ void pair_stats(const float* __restrict__ o1,
                           const float* __restrict__ o2,
                           float* __restrict__ bw)
{
    const int p = blockIdx.x;          // 256 pairs
    const int l = p >> 7, s = p & 127;
    const float* o = l ? o2 : o1;
    const int tid = threadIdx.x;       // 256
    const int h = tid & 127, half = tid >> 7;

    float acc_u = 0.f, acc_sq = 0.f;
    for (int r = 0; r < 256; ++r) {
        int i = half * 256 + r;
        float v = o[((size_t)i * 128 + s) * 128 + h];
        acc_u += v; acc_sq += v * v;
    }
    __shared__ float u2[256];
    __shared__ float red[256];
    u2[tid] = acc_u;
    red[tid] = acc_sq;
    __syncthreads();
    for (int st = 128; st > 0; st >>= 1) {
        if (tid < st) red[tid] += red[tid + st];
        __syncthreads();
    }
    float S1 = red[0];
    __syncthreads();
    float uu = 0.f;
    if (tid < 128) { float t = u2[tid] + u2[tid + 128]; uu = t * t; }
    red[tid] = uu;
    __syncthreads();
    for (int st = 128; st > 0; st >>= 1) {
        if (tid < st) red[tid] += red[tid + st];
        __syncthreads();
    }
    if (tid == 0) {
        float S2 = red[0];
        float d2s = 1024.f * S1 - 2.f * S2;
        bw[p] = d2s / (512.f * 512.f - 512.f) * 0.25f;
    }
}

// ---------------- K9: MMD Gram + 5-kernel sum, symmetric tiles ----------------
// R5 post-mortem: epilogue '#pragma unroll 1' made acc[i][j] runtime-indexed
// -> whole acc array demoted to scratch (VGPR=72, WRITE_SIZE=805MB). ALL acc
// accesses must be statically indexed: full unroll everywhere acc is touched.
__global__ __launch_bounds__(256) void mmd_kern(const float* __restrict__ o1,
                                                const float* __restrict__ o2,
                                                const float* __restrict__ norms,
                                                const float* __restrict__ bw,
                                                float* __restrict__ mmdv)
{
    const int lin = blockIdx.x;               // 0..2559
    const int v   = (lin & 7) * 320 + (lin >> 3);
    const int p   = v / 10;                   // pair
    const int tp  = v - p * 10;               // tile-pair
    int ti, tj;
    if (tp < 4)      { ti = 0; tj = tp; }
    else if (tp < 7) { ti = 1; tj = tp - 3; }
    else if (tp < 9) { ti = 2; tj = tp - 5; }
    else             { ti = 3; tj = 3; }
    const int l = p >> 7, s = p & 127;
    const float* o = l ? o2 : o1;
    const float sgn  = ((ti < 2) == (tj < 2)) ? 1.f : -1.f;
    const float coef = sgn * ((ti == tj) ? 1.f : 2.f);

    __shared__ __align__(16) float As[128][36];
    __shared__ __align__(16) float Bs[128][36];
    __shared__ float rbuf[4];

    const int tid = threadIdx.x;
    const int tx = tid & 15, ty = tid >> 4;

    float acc[8][8];
#pragma unroll
    for (int i = 0; i < 8; ++i)
#pragma unroll
        for (int j = 0; j < 8; ++j) acc[i][j] = 0.f;

#pragma unroll 1
    for (int kc = 0; kc < 128; kc += 32) {
#pragma unroll
        for (int it = 0; it < 4; ++it) {
            int idx = tid + it * 256;           // 0..1023
            int row = idx >> 3;
            int c4  = (idx & 7) * 4;
            float4 va = *(const float4*)(o + ((size_t)(ti * 128 + row) * 128 + s) * 128 + kc + c4);
            *(float4*)&As[row][c4] = va;
            float4 vb = *(const float4*)(o + ((size_t)(tj * 128 + row) * 128 + s) * 128 + kc + c4);
            *(float4*)&Bs[row][c4] = vb;
        }
        __syncthreads();
#pragma unroll 1
        for (int k0 = 0; k0 < 32; k0 += 4) {
            float4 b4[8];
#pragma unroll
            for (int j = 0; j < 8; ++j) b4[j] = *(float4*)&Bs[tx + 16 * j][k0];
#pragma unroll
            for (int i = 0; i < 8; ++i) {
                float4 a4 = *(float4*)&As[ty + 16 * i][k0];
#pragma unroll
                for (int j = 0; j < 8; ++j) {
                    acc[i][j] += a4.x * b4[j].x + a4.y * b4[j].y +
                                 a4.z * b4[j].z + a4.w * b4[j].w;
                }
            }
        }
        __syncthreads();
    }

    const float* np_ = norms + (size_t)p * 512;
    float na[8], nb[8];
#pragma unroll
    for (int i = 0; i < 8; ++i) na[i] = np_[ti * 128 + ty + 16 * i];
#pragma unroll
    for (int j = 0; j < 8; ++j) nb[j] = np_[tj * 128 + tx + 16 * j];

    const float bwv = bw[p];
    float c0 = -1.f / bwv;
    float c1 = c0 * 0.5f, c2 = c1 * 0.5f, c3 = c2 * 0.5f, c4v = c3 * 0.5f;
    float tot = 0.f;
#pragma unroll
    for (int i = 0; i < 8; ++i) {
#pragma unroll
        for (int j = 0; j < 8; ++j) {
            float d2 = na[i] + nb[j] - 2.f * acc[i][j];
            float kv = __expf(c0 * d2) + __expf(c1 * d2) + __expf(c2 * d2) +
                       __expf(c3 * d2) + __expf(c4v * d2);
            tot += kv;
        }
    }
    tot *= coef;

    for (int off = 32; off > 0; off >>= 1) tot += __shfl_down(tot, off);
    if ((tid & 63) == 0) rbuf[tid >> 6] = tot;
    __syncthreads();
    if (tid == 0) atomicAdd(&mmdv[p], rbuf[0] + rbuf[1] + rbuf[2] + rbuf[3]);
}

// ---------------- K10: loss = sum(wts * mmd) / 65536 ----------------
__global__ void final_loss(const float* __restrict__ wts,
                           const float* __restrict__ mmdv,
                           float* __restrict__ out)
{
    const int t = threadIdx.x;  // 256
    float v = wts[t] * mmdv[t];
    __shared__ float red[256];
    red[t] = v;
    __syncthreads();
    for (int st = 128; st > 0; st >>= 1) {
        if (t < st) red[t] += red[t + st];
        __syncthreads();
    }
    if (t == 0) out[0] = red[0] * (1.f / 65536.f);
}

// ---------------- launch ----------------
extern "C" void kernel_launch(void* const* d_in, const int* in_sizes, int n_in,
                              void* d_out, int out_size, void* d_ws, size_t ws_size,
                              hipStream_t stream)
{
    (void)in_sizes; (void)n_in; (void)out_size; (void)ws_size;
    const float* x    = (const float*)d_in[0];
    const float* wih0 = (const float*)d_in[1];
    const float* whh0 = (const float*)d_in[2];
    const float* bih0 = (const float*)d_in[3];
    const float* bhh0 = (const float*)d_in[4];
    const float* wih1 = (const float*)d_in[5];
    const float* whh1 = (const float*)d_in[6];
    const float* bih1 = (const float*)d_in[7];
    const float* bhh1 = (const float*)d_in[8];
    const float* gw0  = (const float*)d_in[9];
    const float* bg0  = (const float*)d_in[11];
    const float* bb0  = (const float*)d_in[12];
    const float* gw1  = (const float*)d_in[13];
    const float* bg1  = (const float*)d_in[15];
    const float* bb1  = (const float*)d_in[16];
    const float* fcw  = (const float*)d_in[17];
    const float* fcb  = (const float*)d_in[18];

    float* out = (float*)d_out;
    char*  ws  = (char*)d_ws;
    float* xw   = (float*)(ws + XW_OFF);
    float* o1   = (float*)(ws + O1_OFF);
    float* o2   = (float*)(ws + O2_OFF);
    float* y0   = (float*)(ws + Y0_OFF);
    float* y1   = (float*)(ws + Y1_OFF);
    float* mmdv = (float*)(ws + MMD_OFF);
    float* wts  = (float*)(ws + WTS_OFF);
    float* bwv  = (float*)(ws + BW_OFF);
    float* nrm  = (float*)(ws + NRM_OFF);   // aliases xw; valid after 2nd gru_scan

    hipMemsetAsync(y0, 0, (256 * 128 * 2 + 256) * sizeof(float), stream);

    gemm64<<<dim3(1024, 6), 256, 0, stream>>>(x, wih0, bih0, xw, 65536, 384, 128);
    gru_scan<<<256, 384, 0, stream>>>(xw, whh0, bhh0, o1);
    gemm64<<<dim3(1024, 6), 256, 0, stream>>>(o1, wih1, bih1, xw, 65536, 384, 128);
    gru_scan<<<256, 384, 0, stream>>>(xw, whh1, bhh1, o2);

    gate_gemm<<<dim3(4, 2, 32), 256, 0, stream>>>(o1, gw0, y0);
    gate_gemm<<<dim3(4, 2, 32), 256, 0, stream>>>(o2, gw1, y1);
    gate_reduce<<<1, 128, 0, stream>>>(y0, bg0, bb0, wts, out + 3073);
    gate_reduce<<<1, 128, 0, stream>>>(y1, bg1, bb1, wts + 128, out + 3073 + 128);

    fc_kern<<<12, 256, 0, stream>>>(o2, fcw, fcb, out);

    row_norms<<<dim3(128, 2), 512, 0, stream>>>(o1, o2, nrm);   // xw dead from here
    pair_stats<<<256, 256, 0, stream>>>(o1, o2, bwv);
    mmd_kern<<<2560, 256, 0, stream>>>(o1, o2, nrm, bwv, mmdv);
    final_loss<<<1, 256, 0, stream>>>(wts, mmdv, out + 3072);
}